// Round 14
// baseline (30.945 us; speedup 1.0000x reference)
//
#include <hip/hip_runtime.h>
#include <cstddef>

#define NB 64
#define NA 5
#define NC 20
#define NH 64
#define NW 64
#define MAXB 50
#define HWSZ (NH * NW)
#define NABLK 64                       // A-blocks (bid 0..63)
#define NBBLK 1280                     // B-blocks: 1280*1024 = 1,310,720 cells
#define NGRID (NABLK + NBBLK)          // 1344

__constant__ float c_aw[NA] = {1.3221f, 3.19275f, 5.05587f, 9.47112f, 11.2364f};
__constant__ float c_ah[NA] = {1.73145f, 4.00944f, 8.09892f, 4.84053f, 10.0071f};

// sigmoid with hardware rcp (v_rcp_f32, ~1ulp): avoids the ~10-instr IEEE divide
__device__ __forceinline__ float sigmoid_fast(float v) {
    return __builtin_amdgcn_rcpf(1.f + __expf(-v));
}

__global__ __launch_bounds__(256, 4) void region_loss_fused(const float* __restrict__ out,
                                                            const float* __restrict__ tgt,
                                                            float* __restrict__ outp) {
    const int bid = blockIdx.x;
    const int t = threadIdx.x;

    __shared__ __align__(16) float sbox[MAXB][8];  // xlo,xhi,ylo,yhi,.375A,gy,gh,garea
    __shared__ float sred[4];

    if (bid < NABLK) {
        // ---------------- A: assigned-cell terms (wave 0 does the work) -------
        __shared__ float s_cls[MAXB], s_gx[MAXB], s_gy[MAXB], s_gw[MAXB], s_gh[MAXB];
        __shared__ int s_flat[MAXB], s_bestn[MAXB];
        __shared__ int s_nv;

        const int b = bid;
        if (t < 64) {
            float xv = (t < MAXB) ? tgt[(size_t)b * (MAXB * 5) + t * 5 + 1] : 0.f;
            unsigned long long mk = __ballot(xv != 0.f);
            unsigned long long inv = (~mk) & ((1ull << MAXB) - 1ull);
            int nv_ = inv ? (__ffsll(inv) - 1) : MAXB;
            if (t == 0) s_nv = nv_;
            if (t < MAXB) {
                bool val = t < nv_;
                const float* tp = tgt + (size_t)b * (MAXB * 5) + t * 5;
                float gx = tp[1] * (float)NW, gy = tp[2] * (float)NH;
                float gw = tp[3] * (float)NW, gh = tp[4] * (float)NH;
                s_cls[t] = tp[0];
                s_gx[t] = gx; s_gy[t] = gy; s_gw[t] = gw; s_gh[t] = gh;
                sbox[t][0] = val ? gx - 0.5f * gw : 0.f;
                sbox[t][1] = val ? gx + 0.5f * gw : 0.f;
                sbox[t][2] = val ? gy - 0.5f * gh : 0.f;
                sbox[t][3] = val ? gy + 0.5f * gh : 0.f;
                sbox[t][4] = val ? 0.375f * gw * gh : 1e30f;
            }
        }
        __syncthreads();
        const int nv = s_nv;

        if (t < MAXB) {
            if (t < nv) {
                float gw = s_gw[t], gh = s_gh[t];
                float best = -1.f; int bn = 0;
#pragma unroll
                for (int a = 0; a < NA; ++a) {
                    float ca = fminf(c_aw[a], gw) * fminf(c_ah[a], gh);
                    float ua = c_aw[a] * c_ah[a] + gw * gh - ca;
                    float iou = ca / ua;
                    if (iou > best) { best = iou; bn = a; }   // first max wins
                }
                int gi = (int)s_gx[t], gj = (int)s_gy[t];
                s_bestn[t] = bn;
                s_flat[t] = (bn * NH + gj) * NW + gi;
            } else {
                s_flat[t] = -1 - t;   // unique, never matches
            }
        }
        __syncthreads();

        float loss = 0.f;
        if (t < nv) {
            // last-writer-wins dedupe, fixed trip count
            bool winner = true;
            const int myf = s_flat[t];
#pragma unroll 10
            for (int t2 = 0; t2 < MAXB; ++t2)
                winner &= (t2 <= t) | (s_flat[t2] != myf);
            if (winner) {
                const int a = s_bestn[t];
                const int gi = myf & (NW - 1);
                const int gj = (myf >> 6) & (NH - 1);
                const size_t base = (((size_t)b * NA + a) * 25) * HWSZ + gj * NW + gi;
                float x = 1.f / (1.f + __expf(-out[base]));
                float y = 1.f / (1.f + __expf(-out[base + HWSZ]));
                float w = __expf(out[base + 2 * HWSZ]);
                float h = __expf(out[base + 3 * HWSZ]);
                float conf = 1.f / (1.f + __expf(-out[base + 4 * HWSZ]));

                float gx = s_gx[t], gy = s_gy[t], gw = s_gw[t], gh = s_gh[t];
                float tx = gx - (float)gi, ty = gy - (float)gj;
                float tw = gw / c_aw[a], th = gh / c_ah[a];
                float dx = x - tx, dy = y - ty, dw = w - tw, dh = h - th;
                loss += 0.5f * (dx * dx + dy * dy + dw * dw + dh * dh);

                float px = x + (float)gi, py = y + (float)gj;
                float pw = w * c_aw[a], ph = h * c_ah[a];
                float pxlo = px - 0.5f * pw, pxhi = px + 0.5f * pw;
                float pylo = py - 0.5f * ph, pyhi = py + 0.5f * ph;
                float parea = pw * ph;

                {   // assigned conf term minus what B added for this cell
                    float cw  = fminf(pxhi, gx + 0.5f * gw) - fmaxf(pxlo, gx - 0.5f * gw);
                    float chh = fminf(pyhi, gy + 0.5f * gh) - fmaxf(pylo, gy - 0.5f * gh);
                    float ca  = fmaxf(cw, 0.f) * fmaxf(chh, 0.f);
                    float ua  = parea + gw * gh - ca;
                    float tconf = ca / ua;
                    float mm = -1e30f;
#pragma unroll 10
                    for (int t2 = 0; t2 < MAXB; ++t2) {
                        const float4 bb = *reinterpret_cast<const float4*>(&sbox[t2][0]);
                        const float s2 = sbox[t2][4];
                        float cw2 = fminf(pxhi, bb.y) - fmaxf(pxlo, bb.x);
                        float ch2 = fminf(pyhi, bb.w) - fmaxf(pylo, bb.z);
                        mm = fmaxf(mm, fmaf(fmaxf(cw2, 0.f), fmaxf(ch2, 0.f), -s2));
                    }
                    bool sil = mm > 0.375f * parea;
                    float base_c = sil ? 0.f : 0.5f * conf * conf;
                    float dc = conf - tconf;
                    loss += 0.5f * dc * dc - base_c;
                }

                {   // class cross-entropy
                    const int lab = (int)s_cls[t];
                    float mmax = -1e30f, llab = 0.f;
#pragma unroll
                    for (int c = 0; c < NC; ++c) {
                        float l = out[base + (size_t)(5 + c) * HWSZ];
                        mmax = fmaxf(mmax, l);
                        if (c == lab) llab = l;
                    }
                    float se = 0.f;
#pragma unroll
                    for (int c = 0; c < NC; ++c)
                        se += __expf(out[base + (size_t)(5 + c) * HWSZ] - mmax);
                    loss += -(llab - mmax - logf(se));
                }
            }
        }
        if (t < 64) {
            for (int off = 32; off; off >>= 1) loss += __shfl_down(loss, off, 64);
            if (t == 0) atomicAdd(outp, loss);
        }
        return;
    }

    // ------- B: no-obj conf loss; 4 consecutive cells/thread, float4 loads ----
    const int g = bid - NABLK;          // 0..1279
    const int b = g / 20;               // 20 blocks per batch (20*1024 = 5*4096)
    const int ba = g >> 2;              // plane index b*5+a (4 blocks per plane)
    const int a = ba - b * NA;
    const int hw = ((g & 3) << 10) + (t << 2);       // thread's first cell in plane
    const int jrow = hw >> 6;                        // all 4 cells share this row

    // wave 0: validity ballot + masked box staging (single wave, no extra sync)
    if (t < 64) {
        float xv = (t < MAXB) ? tgt[(size_t)b * (MAXB * 5) + t * 5 + 1] : 0.f;
        unsigned long long mk = __ballot(xv != 0.f);
        unsigned long long inv = (~mk) & ((1ull << MAXB) - 1ull);
        int nv = inv ? (__ffsll(inv) - 1) : MAXB;
        if (t < MAXB) {
            bool val = t < nv;
            const float* tp = tgt + (size_t)b * (MAXB * 5) + t * 5;
            float gx = tp[1] * (float)NW, gy = tp[2] * (float)NH;
            float gw = tp[3] * (float)NW, gh = tp[4] * (float)NH;
            sbox[t][0] = val ? gx - 0.5f * gw : 0.f;
            sbox[t][1] = val ? gx + 0.5f * gw : 0.f;
            sbox[t][2] = val ? gy - 0.5f * gh : 0.f;
            sbox[t][3] = val ? gy + 0.5f * gh : 0.f;
            sbox[t][4] = val ? 0.375f * gw * gh : 1e30f;  // masked: never silences
            sbox[t][5] = gy;
            sbox[t][6] = val ? gh : -1e9f;                // invalid -> y-test false
            sbox[t][7] = val ? gw * gh : 0.f;             // garea (invalid -> pruned)
        }
    }

    // ---- 5 float4 loads: all memory for this thread's 4 cells ----
    const float* p = out + (size_t)ba * (25 * HWSZ) + hw;
    const float4 vx = *reinterpret_cast<const float4*>(p);
    const float4 vy = *reinterpret_cast<const float4*>(p + HWSZ);
    const float4 vw = *reinterpret_cast<const float4*>(p + 2 * HWSZ);
    const float4 vh = *reinterpret_cast<const float4*>(p + 3 * HWSZ);
    const float4 vc = *reinterpret_cast<const float4*>(p + 4 * HWSZ);

    const float aw = c_aw[a], ah = c_ah[a];
    const float fj = (float)jrow;
    const float fi0 = (float)(hw & 63);

    float pxlo[4], pxhi[4], pylo[4], pyhi[4], m4[4], rhs[4], hc[4];
    {
        const float xs[4] = {vx.x, vx.y, vx.z, vx.w};
        const float ys[4] = {vy.x, vy.y, vy.z, vy.w};
        const float ws[4] = {vw.x, vw.y, vw.z, vw.w};
        const float hs[4] = {vh.x, vh.y, vh.z, vh.w};
        const float cs[4] = {vc.x, vc.y, vc.z, vc.w};
#pragma unroll
        for (int k = 0; k < 4; ++k) {
            float px = sigmoid_fast(xs[k]) + fi0 + (float)k;
            float py = sigmoid_fast(ys[k]) + fj;
            float pw = __expf(ws[k]) * aw;
            float ph = __expf(hs[k]) * ah;
            float cf = sigmoid_fast(cs[k]);
            pxlo[k] = px - 0.5f * pw; pxhi[k] = px + 0.5f * pw;
            pylo[k] = py - 0.5f * ph; pyhi[k] = py + 0.5f * ph;
            rhs[k] = 0.375f * pw * ph;
            hc[k]  = 0.5f * cf * cf;
            m4[k]  = -1e30f;
        }
    }
    __syncthreads();

    // ---- per-wave box mask: y-window (4 rows) + anchor-area window ----------
    const int lane = t & 63;
    const int li = (lane < MAXB) ? lane : 0;
    const float ls_gy = sbox[li][5];
    const float ls_thr = fmaf(0.7334f, sbox[li][6], 2.01f);
    const float ls_ga = sbox[li][7];
    const float A = aw * ah;
    const float midj = (float)(((g & 3) << 4) + ((t >> 6) << 2)) + 2.0f;  // wave j0+2
    bool keep = (lane < MAXB) &&
                (fabsf(midj - ls_gy) < ls_thr) &&
                (A >= 0.0505f * ls_ga) && (A <= 19.8f * ls_ga);
    unsigned long long u = __ballot(keep);

    // ---- pruned box loop (compiler-scheduled LDS reads) ----------------------
    while (u) {
        const int bx = __ffsll(u) - 1;
        u &= u - 1;
        const float4 bb = *reinterpret_cast<const float4*>(&sbox[bx][0]);
        const float s2 = sbox[bx][4];
#pragma unroll
        for (int k = 0; k < 4; ++k) {
            float cw = fminf(pxhi[k], bb.y) - fmaxf(pxlo[k], bb.x);
            float ch = fminf(pyhi[k], bb.w) - fmaxf(pylo[k], bb.z);
            m4[k] = fmaxf(m4[k], fmaf(fmaxf(cw, 0.f), fmaxf(ch, 0.f), -s2));
        }
    }

    float v = 0.f;
#pragma unroll
    for (int k = 0; k < 4; ++k) v += (m4[k] > rhs[k]) ? 0.f : hc[k];

    // block reduce -> one atomic per block (1344 total, spread over the kernel)
    for (int off = 32; off; off >>= 1) v += __shfl_down(v, off, 64);
    if ((t & 63) == 0) sred[t >> 6] = v;
    __syncthreads();
    if (t == 0) atomicAdd(outp, sred[0] + sred[1] + sred[2] + sred[3]);
}

extern "C" void kernel_launch(void* const* d_in, const int* in_sizes, int n_in,
                              void* d_out, int out_size, void* d_ws, size_t ws_size,
                              hipStream_t stream) {
    const float* out_t = (const float*)d_in[0];
    const float* tgt   = (const float*)d_in[1];
    float* loss = (float*)d_out;

    hipMemsetAsync(loss, 0, sizeof(float), stream);   // memset node: re-zeros each replay
    region_loss_fused<<<NGRID, 256, 0, stream>>>(out_t, tgt, loss);
}

// Round 15
// 21.236 us; speedup vs baseline: 1.4572x; 1.4572x over previous
//
#include <hip/hip_runtime.h>
#include <cstddef>

#define NB 64
#define NA 5
#define NC 20
#define NH 64
#define NW 64
#define MAXB 50
#define HWSZ (NH * NW)
#define NABLK 64                       // A-blocks (bid 0..63)
#define NBBLK 1280                     // B-blocks: 1280*1024 = 1,310,720 cells
#define NPART (NABLK + NBBLK)          // 1344

__constant__ float c_aw[NA] = {1.3221f, 3.19275f, 5.05587f, 9.47112f, 11.2364f};
__constant__ float c_ah[NA] = {1.73145f, 4.00944f, 8.09892f, 4.84053f, 10.0071f};

// sigmoid with hardware rcp (v_rcp_f32, ~1ulp): avoids the ~10-instr IEEE divide
__device__ __forceinline__ float sigmoid_fast(float v) {
    return __builtin_amdgcn_rcpf(1.f + __expf(-v));
}

__global__ __launch_bounds__(256, 4) void region_loss_main(const float* __restrict__ out,
                                                           const float* __restrict__ tgt,
                                                           float* __restrict__ partials) {
    const int bid = blockIdx.x;
    const int t = threadIdx.x;

    __shared__ __align__(16) float sbox[MAXB][8];  // xlo,xhi,ylo,yhi,.375A,gy,gh,garea
    __shared__ float s_cls[MAXB], s_gx[MAXB], s_gy[MAXB], s_gw[MAXB], s_gh[MAXB];
    __shared__ int s_flat[MAXB], s_bestn[MAXB];
    __shared__ int s_nv;
    __shared__ float sred[4];

    if (bid < NABLK) {
        // ---------------- A: assigned-cell terms (wave 0 does the work) -------
        const int b = bid;
        if (t < 64) {
            float xv = (t < MAXB) ? tgt[(size_t)b * (MAXB * 5) + t * 5 + 1] : 0.f;
            unsigned long long mk = __ballot(xv != 0.f);
            unsigned long long inv = (~mk) & ((1ull << MAXB) - 1ull);
            int nv_ = inv ? (__ffsll(inv) - 1) : MAXB;
            if (t == 0) s_nv = nv_;
            if (t < MAXB) {
                bool val = t < nv_;
                const float* tp = tgt + (size_t)b * (MAXB * 5) + t * 5;
                float gx = tp[1] * (float)NW, gy = tp[2] * (float)NH;
                float gw = tp[3] * (float)NW, gh = tp[4] * (float)NH;
                s_cls[t] = tp[0];
                s_gx[t] = gx; s_gy[t] = gy; s_gw[t] = gw; s_gh[t] = gh;
                sbox[t][0] = val ? gx - 0.5f * gw : 0.f;
                sbox[t][1] = val ? gx + 0.5f * gw : 0.f;
                sbox[t][2] = val ? gy - 0.5f * gh : 0.f;
                sbox[t][3] = val ? gy + 0.5f * gh : 0.f;
                sbox[t][4] = val ? 0.375f * gw * gh : 1e30f;
            }
        }
        __syncthreads();
        const int nv = s_nv;

        if (t < MAXB) {
            if (t < nv) {
                float gw = s_gw[t], gh = s_gh[t];
                float best = -1.f; int bn = 0;
#pragma unroll
                for (int a = 0; a < NA; ++a) {
                    float ca = fminf(c_aw[a], gw) * fminf(c_ah[a], gh);
                    float ua = c_aw[a] * c_ah[a] + gw * gh - ca;
                    float iou = ca / ua;
                    if (iou > best) { best = iou; bn = a; }   // first max wins
                }
                int gi = (int)s_gx[t], gj = (int)s_gy[t];
                s_bestn[t] = bn;
                s_flat[t] = (bn * NH + gj) * NW + gi;
            } else {
                s_flat[t] = -1 - t;   // unique, never matches
            }
        }
        __syncthreads();

        float loss = 0.f;
        if (t < nv) {
            // last-writer-wins dedupe, fixed trip count
            bool winner = true;
            const int myf = s_flat[t];
#pragma unroll 10
            for (int t2 = 0; t2 < MAXB; ++t2)
                winner &= (t2 <= t) | (s_flat[t2] != myf);
            if (winner) {
                const int a = s_bestn[t];
                const int gi = myf & (NW - 1);
                const int gj = (myf >> 6) & (NH - 1);
                const size_t base = (((size_t)b * NA + a) * 25) * HWSZ + gj * NW + gi;
                float x = 1.f / (1.f + __expf(-out[base]));
                float y = 1.f / (1.f + __expf(-out[base + HWSZ]));
                float w = __expf(out[base + 2 * HWSZ]);
                float h = __expf(out[base + 3 * HWSZ]);
                float conf = 1.f / (1.f + __expf(-out[base + 4 * HWSZ]));

                float gx = s_gx[t], gy = s_gy[t], gw = s_gw[t], gh = s_gh[t];
                float tx = gx - (float)gi, ty = gy - (float)gj;
                float tw = gw / c_aw[a], th = gh / c_ah[a];
                float dx = x - tx, dy = y - ty, dw = w - tw, dh = h - th;
                loss += 0.5f * (dx * dx + dy * dy + dw * dw + dh * dh);

                float px = x + (float)gi, py = y + (float)gj;
                float pw = w * c_aw[a], ph = h * c_ah[a];
                float pxlo = px - 0.5f * pw, pxhi = px + 0.5f * pw;
                float pylo = py - 0.5f * ph, pyhi = py + 0.5f * ph;
                float parea = pw * ph;

                {   // assigned conf term minus what B added for this cell
                    float cw  = fminf(pxhi, gx + 0.5f * gw) - fmaxf(pxlo, gx - 0.5f * gw);
                    float chh = fminf(pyhi, gy + 0.5f * gh) - fmaxf(pylo, gy - 0.5f * gh);
                    float ca  = fmaxf(cw, 0.f) * fmaxf(chh, 0.f);
                    float ua  = parea + gw * gh - ca;
                    float tconf = ca / ua;
                    float mm = -1e30f;
#pragma unroll 10
                    for (int t2 = 0; t2 < MAXB; ++t2) {
                        const float4 bb = *reinterpret_cast<const float4*>(&sbox[t2][0]);
                        const float s2 = sbox[t2][4];
                        float cw2 = fminf(pxhi, bb.y) - fmaxf(pxlo, bb.x);
                        float ch2 = fminf(pyhi, bb.w) - fmaxf(pylo, bb.z);
                        mm = fmaxf(mm, fmaf(fmaxf(cw2, 0.f), fmaxf(ch2, 0.f), -s2));
                    }
                    bool sil = mm > 0.375f * parea;
                    float base_c = sil ? 0.f : 0.5f * conf * conf;
                    float dc = conf - tconf;
                    loss += 0.5f * dc * dc - base_c;
                }

                {   // class cross-entropy
                    const int lab = (int)s_cls[t];
                    float mmax = -1e30f, llab = 0.f;
#pragma unroll
                    for (int c = 0; c < NC; ++c) {
                        float l = out[base + (size_t)(5 + c) * HWSZ];
                        mmax = fmaxf(mmax, l);
                        if (c == lab) llab = l;
                    }
                    float se = 0.f;
#pragma unroll
                    for (int c = 0; c < NC; ++c)
                        se += __expf(out[base + (size_t)(5 + c) * HWSZ] - mmax);
                    loss += -(llab - mmax - logf(se));
                }
            }
        }
        if (t < 64) {
            for (int off = 32; off; off >>= 1) loss += __shfl_down(loss, off, 64);
            if (t == 0) partials[bid] = loss;
        }
        return;
    }

    // ------- B: no-obj conf loss; 4 consecutive cells/thread, float4 loads ----
    const int g = bid - NABLK;          // 0..1279
    const int b = g / 20;               // 20 blocks per batch (20*1024 = 5*4096)
    const int ba = g >> 2;              // plane index b*5+a (4 blocks per plane)
    const int a = ba - b * NA;
    const int hw = ((g & 3) << 10) + (t << 2);       // thread's first cell in plane
    const int jrow = hw >> 6;                        // all 4 cells share this row

    // wave 0: validity ballot + masked box staging (single wave, no extra sync)
    if (t < 64) {
        float xv = (t < MAXB) ? tgt[(size_t)b * (MAXB * 5) + t * 5 + 1] : 0.f;
        unsigned long long mk = __ballot(xv != 0.f);
        unsigned long long inv = (~mk) & ((1ull << MAXB) - 1ull);
        int nv = inv ? (__ffsll(inv) - 1) : MAXB;
        if (t < MAXB) {
            bool val = t < nv;
            const float* tp = tgt + (size_t)b * (MAXB * 5) + t * 5;
            float gx = tp[1] * (float)NW, gy = tp[2] * (float)NH;
            float gw = tp[3] * (float)NW, gh = tp[4] * (float)NH;
            sbox[t][0] = val ? gx - 0.5f * gw : 0.f;
            sbox[t][1] = val ? gx + 0.5f * gw : 0.f;
            sbox[t][2] = val ? gy - 0.5f * gh : 0.f;
            sbox[t][3] = val ? gy + 0.5f * gh : 0.f;
            sbox[t][4] = val ? 0.375f * gw * gh : 1e30f;  // masked: never silences
            sbox[t][5] = gy;
            sbox[t][6] = val ? gh : -1e9f;                // invalid -> y-test false
            sbox[t][7] = val ? gw * gh : 0.f;             // garea (invalid -> pruned)
        }
    }

    // ---- 5 float4 loads: all memory for this thread's 4 cells ----
    const float* p = out + (size_t)ba * (25 * HWSZ) + hw;
    const float4 vx = *reinterpret_cast<const float4*>(p);
    const float4 vy = *reinterpret_cast<const float4*>(p + HWSZ);
    const float4 vw = *reinterpret_cast<const float4*>(p + 2 * HWSZ);
    const float4 vh = *reinterpret_cast<const float4*>(p + 3 * HWSZ);
    const float4 vc = *reinterpret_cast<const float4*>(p + 4 * HWSZ);

    const float aw = c_aw[a], ah = c_ah[a];
    const float fj = (float)jrow;
    const float fi0 = (float)(hw & 63);

    float pxlo[4], pxhi[4], pylo[4], pyhi[4], m4[4], rhs[4], hc[4];
    {
        const float xs[4] = {vx.x, vx.y, vx.z, vx.w};
        const float ys[4] = {vy.x, vy.y, vy.z, vy.w};
        const float ws[4] = {vw.x, vw.y, vw.z, vw.w};
        const float hs[4] = {vh.x, vh.y, vh.z, vh.w};
        const float cs[4] = {vc.x, vc.y, vc.z, vc.w};
#pragma unroll
        for (int k = 0; k < 4; ++k) {
            float px = sigmoid_fast(xs[k]) + fi0 + (float)k;
            float py = sigmoid_fast(ys[k]) + fj;
            float pw = __expf(ws[k]) * aw;
            float ph = __expf(hs[k]) * ah;
            float cf = sigmoid_fast(cs[k]);
            pxlo[k] = px - 0.5f * pw; pxhi[k] = px + 0.5f * pw;
            pylo[k] = py - 0.5f * ph; pyhi[k] = py + 0.5f * ph;
            rhs[k] = 0.375f * pw * ph;
            hc[k]  = 0.5f * cf * cf;
            m4[k]  = -1e30f;
        }
    }
    __syncthreads();

    // ---- per-wave box mask: y-window (4 rows) + anchor-area window ----------
    const int lane = t & 63;
    const int li = (lane < MAXB) ? lane : 0;
    const float ls_gy = sbox[li][5];
    const float ls_thr = fmaf(0.7334f, sbox[li][6], 2.01f);
    const float ls_ga = sbox[li][7];
    const float A = aw * ah;
    const float midj = (float)(((g & 3) << 4) + ((t >> 6) << 2)) + 2.0f;  // wave j0+2
    bool keep = (lane < MAXB) &&
                (fabsf(midj - ls_gy) < ls_thr) &&
                (A >= 0.0505f * ls_ga) && (A <= 19.8f * ls_ga);
    unsigned long long u = __ballot(keep);

    // ---- pruned box loop (compiler-scheduled LDS reads) ----------------------
    while (u) {
        const int bx = __ffsll(u) - 1;
        u &= u - 1;
        const float4 bb = *reinterpret_cast<const float4*>(&sbox[bx][0]);
        const float s2 = sbox[bx][4];
#pragma unroll
        for (int k = 0; k < 4; ++k) {
            float cw = fminf(pxhi[k], bb.y) - fmaxf(pxlo[k], bb.x);
            float ch = fminf(pyhi[k], bb.w) - fmaxf(pylo[k], bb.z);
            m4[k] = fmaxf(m4[k], fmaf(fmaxf(cw, 0.f), fmaxf(ch, 0.f), -s2));
        }
    }

    float v = 0.f;
#pragma unroll
    for (int k = 0; k < 4; ++k) v += (m4[k] > rhs[k]) ? 0.f : hc[k];

    for (int off = 32; off; off >>= 1) v += __shfl_down(v, off, 64);
    if ((t & 63) == 0) sred[t >> 6] = v;
    __syncthreads();
    if (t == 0) partials[bid] = sred[0] + sred[1] + sred[2] + sred[3];
}

// ---------------- deterministic final reduce (2nd graph node) ----------------
__global__ __launch_bounds__(256) void reduce_kernel(const float* __restrict__ partials,
                                                     float* __restrict__ outp) {
    float v = 0.f;
    for (int idx = threadIdx.x; idx < NPART; idx += 256) v += partials[idx];
    for (int off = 32; off; off >>= 1) v += __shfl_down(v, off, 64);
    __shared__ float s[4];
    if ((threadIdx.x & 63) == 0) s[threadIdx.x >> 6] = v;
    __syncthreads();
    if (threadIdx.x == 0) outp[0] = s[0] + s[1] + s[2] + s[3];
}

extern "C" void kernel_launch(void* const* d_in, const int* in_sizes, int n_in,
                              void* d_out, int out_size, void* d_ws, size_t ws_size,
                              hipStream_t stream) {
    const float* out_t = (const float*)d_in[0];
    const float* tgt   = (const float*)d_in[1];
    float* loss = (float*)d_out;
    float* partials = (float*)d_ws;   // NPART floats, fully rewritten each call

    region_loss_main<<<NPART, 256, 0, stream>>>(out_t, tgt, partials);
    reduce_kernel<<<1, 256, 0, stream>>>(partials, loss);
}

// Round 16
// 21.000 us; speedup vs baseline: 1.4736x; 1.0113x over previous
//
#include <hip/hip_runtime.h>
#include <cstddef>

#define NB 64
#define NA 5
#define NC 20
#define NH 64
#define NW 64
#define MAXB 50
#define HWSZ (NH * NW)
#define NABLK 64                       // A-blocks (bid 0..63)
#define NBBLK 1280                     // B-blocks: 1280*1024 = 1,310,720 cells
#define NPART (NABLK + NBBLK)          // 1344

__constant__ float c_aw[NA] = {1.3221f, 3.19275f, 5.05587f, 9.47112f, 11.2364f};
__constant__ float c_ah[NA] = {1.73145f, 4.00944f, 8.09892f, 4.84053f, 10.0071f};
// reciprocals (host-computed, ~1e-6 rel err; threshold is 2%)
__constant__ float c_rw[NA] = {0.7563725f, 0.3132096f, 0.1977899f, 0.1055842f, 0.0889964f};
__constant__ float c_rh[NA] = {0.5775506f, 0.2494114f, 0.1234733f, 0.2065889f, 0.0999291f};

// sigmoid with hardware rcp (v_rcp_f32, ~1ulp): avoids the ~15-instr IEEE divide
__device__ __forceinline__ float sigmoid_fast(float v) {
    return __builtin_amdgcn_rcpf(1.f + __expf(-v));
}

__global__ __launch_bounds__(256, 4) void region_loss_main(const float* __restrict__ out,
                                                           const float* __restrict__ tgt,
                                                           float* __restrict__ partials) {
    const int bid = blockIdx.x;
    const int t = threadIdx.x;

    __shared__ __align__(16) float sbox[MAXB][8];  // xlo,xhi,ylo,yhi,.375A,gy,gh,garea
    __shared__ float s_cls[MAXB], s_gx[MAXB], s_gy[MAXB], s_gw[MAXB], s_gh[MAXB];
    __shared__ int s_flat[MAXB], s_bestn[MAXB];
    __shared__ int s_nv;
    __shared__ float sred[4];

    if (bid < NABLK) {
        // ---------------- A: assigned-cell terms (wave 0 does the work) -------
        const int b = bid;
        if (t < 64) {
            float xv = (t < MAXB) ? tgt[(size_t)b * (MAXB * 5) + t * 5 + 1] : 0.f;
            unsigned long long mk = __ballot(xv != 0.f);
            unsigned long long inv = (~mk) & ((1ull << MAXB) - 1ull);
            int nv_ = inv ? (__ffsll(inv) - 1) : MAXB;
            if (t == 0) s_nv = nv_;
            if (t < MAXB) {
                bool val = t < nv_;
                const float* tp = tgt + (size_t)b * (MAXB * 5) + t * 5;
                float gx = tp[1] * (float)NW, gy = tp[2] * (float)NH;
                float gw = tp[3] * (float)NW, gh = tp[4] * (float)NH;
                s_cls[t] = tp[0];
                s_gx[t] = gx; s_gy[t] = gy; s_gw[t] = gw; s_gh[t] = gh;
                sbox[t][0] = val ? gx - 0.5f * gw : 0.f;
                sbox[t][1] = val ? gx + 0.5f * gw : 0.f;
                sbox[t][2] = val ? gy - 0.5f * gh : 0.f;
                sbox[t][3] = val ? gy + 0.5f * gh : 0.f;
                sbox[t][4] = val ? 0.375f * gw * gh : 1e30f;
            }
        }
        __syncthreads();
        const int nv = s_nv;

        if (t < MAXB) {
            if (t < nv) {
                float gw = s_gw[t], gh = s_gh[t];
                float best = -1.f; int bn = 0;
#pragma unroll
                for (int a = 0; a < NA; ++a) {
                    float ca = fminf(c_aw[a], gw) * fminf(c_ah[a], gh);
                    float ua = c_aw[a] * c_ah[a] + gw * gh - ca;
                    float iou = ca * __builtin_amdgcn_rcpf(ua);
                    if (iou > best) { best = iou; bn = a; }   // first max wins
                }
                int gi = (int)s_gx[t], gj = (int)s_gy[t];
                s_bestn[t] = bn;
                s_flat[t] = (bn * NH + gj) * NW + gi;
            } else {
                s_flat[t] = -1 - t;   // unique, never matches
            }
        }
        __syncthreads();

        float loss = 0.f;
        if (t < nv) {
            // last-writer-wins dedupe, fixed trip count
            bool winner = true;
            const int myf = s_flat[t];
#pragma unroll 10
            for (int t2 = 0; t2 < MAXB; ++t2)
                winner &= (t2 <= t) | (s_flat[t2] != myf);
            if (winner) {
                const int a = s_bestn[t];
                const int gi = myf & (NW - 1);
                const int gj = (myf >> 6) & (NH - 1);
                const size_t base = (((size_t)b * NA + a) * 25) * HWSZ + gj * NW + gi;
                float x = sigmoid_fast(out[base]);
                float y = sigmoid_fast(out[base + HWSZ]);
                float w = __expf(out[base + 2 * HWSZ]);
                float h = __expf(out[base + 3 * HWSZ]);
                float conf = sigmoid_fast(out[base + 4 * HWSZ]);

                float gx = s_gx[t], gy = s_gy[t], gw = s_gw[t], gh = s_gh[t];
                float tx = gx - (float)gi, ty = gy - (float)gj;
                float tw = gw * c_rw[a], th = gh * c_rh[a];
                float dx = x - tx, dy = y - ty, dw = w - tw, dh = h - th;
                loss += 0.5f * (dx * dx + dy * dy + dw * dw + dh * dh);

                float px = x + (float)gi, py = y + (float)gj;
                float pw = w * c_aw[a], ph = h * c_ah[a];
                float pxlo = px - 0.5f * pw, pxhi = px + 0.5f * pw;
                float pylo = py - 0.5f * ph, pyhi = py + 0.5f * ph;
                float parea = pw * ph;

                {   // assigned conf term minus what B added for this cell
                    float cw  = fminf(pxhi, gx + 0.5f * gw) - fmaxf(pxlo, gx - 0.5f * gw);
                    float chh = fminf(pyhi, gy + 0.5f * gh) - fmaxf(pylo, gy - 0.5f * gh);
                    float ca  = fmaxf(cw, 0.f) * fmaxf(chh, 0.f);
                    float ua  = parea + gw * gh - ca;
                    float tconf = ca * __builtin_amdgcn_rcpf(ua);
                    float mm = -1e30f;
#pragma unroll 10
                    for (int t2 = 0; t2 < MAXB; ++t2) {
                        const float4 bb = *reinterpret_cast<const float4*>(&sbox[t2][0]);
                        const float s2 = sbox[t2][4];
                        float cw2 = fminf(pxhi, bb.y) - fmaxf(pxlo, bb.x);
                        float ch2 = fminf(pyhi, bb.w) - fmaxf(pylo, bb.z);
                        mm = fmaxf(mm, fmaf(fmaxf(cw2, 0.f), fmaxf(ch2, 0.f), -s2));
                    }
                    bool sil = mm > 0.375f * parea;
                    float base_c = sil ? 0.f : 0.5f * conf * conf;
                    float dc = conf - tconf;
                    loss += 0.5f * dc * dc - base_c;
                }

                {   // class cross-entropy: single pass, logits cached in registers
                    const int lab = (int)s_cls[t];
                    float lv[NC];
                    float mmax = -1e30f, llab = 0.f;
#pragma unroll
                    for (int c = 0; c < NC; ++c) {
                        lv[c] = out[base + (size_t)(5 + c) * HWSZ];
                        mmax = fmaxf(mmax, lv[c]);
                        if (c == lab) llab = lv[c];
                    }
                    float se = 0.f;
#pragma unroll
                    for (int c = 0; c < NC; ++c)
                        se += __expf(lv[c] - mmax);
                    loss += -(llab - mmax - logf(se));
                }
            }
        }
        if (t < 64) {
            for (int off = 32; off; off >>= 1) loss += __shfl_down(loss, off, 64);
            if (t == 0) partials[bid] = loss;
        }
        return;
    }

    // ------- B: no-obj conf loss; 4 consecutive cells/thread, float4 loads ----
    const int g = bid - NABLK;          // 0..1279
    const int b = g / 20;               // 20 blocks per batch (20*1024 = 5*4096)
    const int ba = g >> 2;              // plane index b*5+a (4 blocks per plane)
    const int a = ba - b * NA;
    const int hw = ((g & 3) << 10) + (t << 2);       // thread's first cell in plane
    const int jrow = hw >> 6;                        // all 4 cells share this row

    // wave 0: validity ballot + masked box staging (single wave, no extra sync)
    if (t < 64) {
        float xv = (t < MAXB) ? tgt[(size_t)b * (MAXB * 5) + t * 5 + 1] : 0.f;
        unsigned long long mk = __ballot(xv != 0.f);
        unsigned long long inv = (~mk) & ((1ull << MAXB) - 1ull);
        int nv = inv ? (__ffsll(inv) - 1) : MAXB;
        if (t < MAXB) {
            bool val = t < nv;
            const float* tp = tgt + (size_t)b * (MAXB * 5) + t * 5;
            float gx = tp[1] * (float)NW, gy = tp[2] * (float)NH;
            float gw = tp[3] * (float)NW, gh = tp[4] * (float)NH;
            sbox[t][0] = val ? gx - 0.5f * gw : 0.f;
            sbox[t][1] = val ? gx + 0.5f * gw : 0.f;
            sbox[t][2] = val ? gy - 0.5f * gh : 0.f;
            sbox[t][3] = val ? gy + 0.5f * gh : 0.f;
            sbox[t][4] = val ? 0.375f * gw * gh : 1e30f;  // masked: never silences
            sbox[t][5] = gy;
            sbox[t][6] = val ? gh : -1e9f;                // invalid -> y-test false
            sbox[t][7] = val ? gw * gh : 0.f;             // garea (invalid -> pruned)
        }
    }

    // ---- 5 float4 loads: all memory for this thread's 4 cells ----
    const float* p = out + (size_t)ba * (25 * HWSZ) + hw;
    const float4 vx = *reinterpret_cast<const float4*>(p);
    const float4 vy = *reinterpret_cast<const float4*>(p + HWSZ);
    const float4 vw = *reinterpret_cast<const float4*>(p + 2 * HWSZ);
    const float4 vh = *reinterpret_cast<const float4*>(p + 3 * HWSZ);
    const float4 vc = *reinterpret_cast<const float4*>(p + 4 * HWSZ);

    const float aw = c_aw[a], ah = c_ah[a];
    const float fj = (float)jrow;
    const float fi0 = (float)(hw & 63);

    float pxlo[4], pxhi[4], pylo[4], pyhi[4], m4[4], rhs[4], hc[4];
    {
        const float xs[4] = {vx.x, vx.y, vx.z, vx.w};
        const float ys[4] = {vy.x, vy.y, vy.z, vy.w};
        const float ws[4] = {vw.x, vw.y, vw.z, vw.w};
        const float hs[4] = {vh.x, vh.y, vh.z, vh.w};
        const float cs[4] = {vc.x, vc.y, vc.z, vc.w};
#pragma unroll
        for (int k = 0; k < 4; ++k) {
            float px = sigmoid_fast(xs[k]) + fi0 + (float)k;
            float py = sigmoid_fast(ys[k]) + fj;
            float pw = __expf(ws[k]) * aw;
            float ph = __expf(hs[k]) * ah;
            float cf = sigmoid_fast(cs[k]);
            pxlo[k] = px - 0.5f * pw; pxhi[k] = px + 0.5f * pw;
            pylo[k] = py - 0.5f * ph; pyhi[k] = py + 0.5f * ph;
            rhs[k] = 0.375f * pw * ph;
            hc[k]  = 0.5f * cf * cf;
            m4[k]  = -1e30f;
        }
    }
    __syncthreads();

    // ---- per-wave box mask: y-window (4 rows) + anchor-area window ----------
    const int lane = t & 63;
    const int li = (lane < MAXB) ? lane : 0;
    const float ls_gy = sbox[li][5];
    const float ls_thr = fmaf(0.7334f, sbox[li][6], 2.01f);
    const float ls_ga = sbox[li][7];
    const float A = aw * ah;
    const float midj = (float)(((g & 3) << 4) + ((t >> 6) << 2)) + 2.0f;  // wave j0+2
    bool keep = (lane < MAXB) &&
                (fabsf(midj - ls_gy) < ls_thr) &&
                (A >= 0.0505f * ls_ga) && (A <= 19.8f * ls_ga);
    unsigned long long u = __ballot(keep);

    // ---- pruned box loop (compiler-scheduled LDS reads) ----------------------
    while (u) {
        const int bx = __ffsll(u) - 1;
        u &= u - 1;
        const float4 bb = *reinterpret_cast<const float4*>(&sbox[bx][0]);
        const float s2 = sbox[bx][4];
#pragma unroll
        for (int k = 0; k < 4; ++k) {
            float cw = fminf(pxhi[k], bb.y) - fmaxf(pxlo[k], bb.x);
            float ch = fminf(pyhi[k], bb.w) - fmaxf(pylo[k], bb.z);
            m4[k] = fmaxf(m4[k], fmaf(fmaxf(cw, 0.f), fmaxf(ch, 0.f), -s2));
        }
    }

    float v = 0.f;
#pragma unroll
    for (int k = 0; k < 4; ++k) v += (m4[k] > rhs[k]) ? 0.f : hc[k];

    for (int off = 32; off; off >>= 1) v += __shfl_down(v, off, 64);
    if ((t & 63) == 0) sred[t >> 6] = v;
    __syncthreads();
    if (t == 0) partials[bid] = sred[0] + sred[1] + sred[2] + sred[3];
}

// ---------------- deterministic final reduce (2nd graph node) ----------------
__global__ __launch_bounds__(256) void reduce_kernel(const float* __restrict__ partials,
                                                     float* __restrict__ outp) {
    float v = 0.f;
    for (int idx = threadIdx.x; idx < NPART; idx += 256) v += partials[idx];
    for (int off = 32; off; off >>= 1) v += __shfl_down(v, off, 64);
    __shared__ float s[4];
    if ((threadIdx.x & 63) == 0) s[threadIdx.x >> 6] = v;
    __syncthreads();
    if (threadIdx.x == 0) outp[0] = s[0] + s[1] + s[2] + s[3];
}

extern "C" void kernel_launch(void* const* d_in, const int* in_sizes, int n_in,
                              void* d_out, int out_size, void* d_ws, size_t ws_size,
                              hipStream_t stream) {
    const float* out_t = (const float*)d_in[0];
    const float* tgt   = (const float*)d_in[1];
    float* loss = (float*)d_out;
    float* partials = (float*)d_ws;   // NPART floats, fully rewritten each call

    region_loss_main<<<NPART, 256, 0, stream>>>(out_t, tgt, partials);
    reduce_kernel<<<1, 256, 0, stream>>>(partials, loss);
}